// Round 1
// baseline (486.609 us; speedup 1.0000x reference)
//
#include <hip/hip_runtime.h>
#include <hip/hip_bf16.h>
#include <math.h>

#define BS 16
#define M  16
#define T  32
#define V  12000
#define P  64
#define PV 20

// ---------------------------------------------------------------------------
// Caption CE: one block per (b,m,t) row. Early-exit masked rows (no HBM read).
// Online softmax over V=12000 with float4 loads (3000 float4 per row, aligned).
// ---------------------------------------------------------------------------
__global__ __launch_bounds__(256) void cap_loss_kernel(
    const float* __restrict__ pred,        // [BS,M,T,V]
    const int*   __restrict__ gt,          // [BS,M,T]
    const int*   __restrict__ cap_lens,    // [BS,M]
    const int*   __restrict__ caps_count,  // [BS]
    float*       __restrict__ acc)         // acc[0] += nll
{
    const int row = blockIdx.x;            // 0 .. BS*M*T-1
    const int t   = row % T;
    const int bm  = row / T;
    const int m   = bm % M;
    const int b   = bm / M;

    // mask: token valid iff t < cap_len AND m < caps_count
    if (t >= cap_lens[bm] || m >= caps_count[b]) return;

    const float4* p4 = (const float4*)(pred + (size_t)row * V);
    const int NV4 = V / 4;                 // 3000

    float lmax = -INFINITY;
    float lsum = 0.0f;
    for (int i = threadIdx.x; i < NV4; i += 256) {
        float4 x = p4[i];
        float m4 = fmaxf(fmaxf(x.x, x.y), fmaxf(x.z, x.w));
        float nm = fmaxf(lmax, m4);
        lsum = lsum * __expf(lmax - nm)
             + __expf(x.x - nm) + __expf(x.y - nm)
             + __expf(x.z - nm) + __expf(x.w - nm);
        lmax = nm;
    }

    // wave (64-lane) online-softmax merge
    for (int off = 32; off > 0; off >>= 1) {
        float om = __shfl_down(lmax, off, 64);
        float os = __shfl_down(lsum, off, 64);
        float nm = fmaxf(lmax, om);
        lsum = lsum * __expf(lmax - nm) + os * __expf(om - nm);
        lmax = nm;
    }

    __shared__ float sm[4], ss[4];
    const int wave = threadIdx.x >> 6;
    const int lane = threadIdx.x & 63;
    if (lane == 0) { sm[wave] = lmax; ss[wave] = lsum; }
    __syncthreads();

    if (threadIdx.x == 0) {
        float gm = sm[0], gs = ss[0];
        #pragma unroll
        for (int w = 1; w < 4; w++) {
            float nm = fmaxf(gm, sm[w]);
            gs = gs * __expf(gm - nm) + ss[w] * __expf(sm[w] - nm);
            gm = nm;
        }
        const float xg  = pred[(size_t)row * V + gt[row]];
        const float nll = logf(gs) + gm - xg;   // -(xg - gm - log(sum))
        atomicAdd(acc, nll);
    }
}

// ---------------------------------------------------------------------------
// Program CE: 1024 rows of PV=20. One thread per row.
// ---------------------------------------------------------------------------
__global__ __launch_bounds__(256) void prog_loss_kernel(
    const float* __restrict__ pred_prog,   // [BS,P,PV]
    const int*   __restrict__ gt_prog,     // [BS,P]
    const int*   __restrict__ prog_len,    // [BS]
    float*       __restrict__ acc)         // acc[1] += nll
{
    const int idx = blockIdx.x * blockDim.x + threadIdx.x;  // 0..1023
    const int p   = idx % P;
    const int b   = idx / P;

    float nll = 0.0f;
    if (p < prog_len[b]) {
        const float* row = pred_prog + (size_t)idx * PV;
        float mx = row[0];
        #pragma unroll
        for (int i = 1; i < PV; i++) mx = fmaxf(mx, row[i]);
        float s = 0.0f;
        #pragma unroll
        for (int i = 0; i < PV; i++) s += __expf(row[i] - mx);
        nll = logf(s) + mx - row[gt_prog[idx]];
    }
    for (int off = 32; off > 0; off >>= 1) nll += __shfl_down(nll, off, 64);
    if ((threadIdx.x & 63) == 0) atomicAdd(acc + 1, nll);
}

// ---------------------------------------------------------------------------
// Final: single block. IoU sum + exact ragged counts + divisions + output.
// ---------------------------------------------------------------------------
__global__ __launch_bounds__(256) void final_kernel(
    const int*   __restrict__ cap_lens,     // [BS,M]
    const int*   __restrict__ caps_count,   // [BS]
    const int*   __restrict__ prog_len,     // [BS]
    const float* __restrict__ gt_iv,        // [BS,M,2]
    const float* __restrict__ pred_iv,      // [BS,M,2]
    const float* __restrict__ acc,          // [cap_sum, prog_sum]
    float*       __restrict__ out)          // [loss, cap, prog, iou]
{
    const int idx = threadIdx.x;            // 0..255 == b*M + m
    const int m = idx % M, b = idx / M;
    const int cc = caps_count[b];

    float ntok = (m < cc) ? (float)cap_lens[idx] : 0.0f;

    float iou = 0.0f;
    if (m < cc) {
        const float gs = gt_iv[idx * 2], ge = gt_iv[idx * 2 + 1];
        const float ps = pred_iv[idx * 2], pe = pred_iv[idx * 2 + 1];
        float inter = fminf(pe, ge) - fmaxf(ps, gs);
        inter = fmaxf(inter, 0.0f);
        const float uni = fmaxf(pe, ge) - fminf(ps, gs);
        iou = inter / fmaxf(uni, 1e-8f);
    }
    float nprog = (idx < BS) ? (float)prog_len[idx]   : 0.0f;
    float ncaps = (idx < BS) ? (float)caps_count[idx] : 0.0f;

    __shared__ float s_tok[256], s_iou[256], s_np[256], s_nc[256];
    s_tok[idx] = ntok; s_iou[idx] = iou; s_np[idx] = nprog; s_nc[idx] = ncaps;
    __syncthreads();
    for (int off = 128; off > 0; off >>= 1) {
        if (idx < off) {
            s_tok[idx] += s_tok[idx + off];
            s_iou[idx] += s_iou[idx + off];
            s_np[idx]  += s_np[idx + off];
            s_nc[idx]  += s_nc[idx + off];
        }
        __syncthreads();
    }
    if (idx == 0) {
        const float cap_loss  = acc[0] / fmaxf(s_tok[0], 1.0f);
        const float prog_loss = acc[1] / fmaxf(s_np[0], 1.0f);
        const float iou_loss  = 1.0f - s_iou[0] / fmaxf(s_nc[0], 1.0f);
        out[0] = cap_loss + prog_loss;
        out[1] = cap_loss;
        out[2] = prog_loss;
        out[3] = iou_loss;
    }
}

extern "C" void kernel_launch(void* const* d_in, const int* in_sizes, int n_in,
                              void* d_out, int out_size, void* d_ws, size_t ws_size,
                              hipStream_t stream) {
    const int*   gt_captions    = (const int*)  d_in[0];
    const int*   gt_cap_lens    = (const int*)  d_in[1];
    const float* pred_captions  = (const float*)d_in[2];
    const int*   gt_program     = (const int*)  d_in[3];
    const int*   gt_prog_len    = (const int*)  d_in[4];
    const float* pred_program   = (const float*)d_in[5];
    const float* gt_intervals   = (const float*)d_in[6];
    const float* pred_intervals = (const float*)d_in[7];
    const int*   gt_caps_count  = (const int*)  d_in[8];
    // d_in[9] (pred_caps_count) is unused by the reference math.

    float* out = (float*)d_out;
    float* acc = (float*)d_ws;   // acc[0]=cap_nll_sum, acc[1]=prog_nll_sum

    hipMemsetAsync(acc, 0, 2 * sizeof(float), stream);

    cap_loss_kernel<<<BS * M * T, 256, 0, stream>>>(
        pred_captions, gt_captions, gt_cap_lens, gt_caps_count, acc);

    prog_loss_kernel<<<(BS * P) / 256, 256, 0, stream>>>(
        pred_program, gt_program, gt_prog_len, acc);

    final_kernel<<<1, 256, 0, stream>>>(
        gt_cap_lens, gt_caps_count, gt_prog_len,
        gt_intervals, pred_intervals, acc, out);
}

// Round 2
// 484.635 us; speedup vs baseline: 1.0041x; 1.0041x over previous
//
#include <hip/hip_runtime.h>
#include <hip/hip_bf16.h>
#include <math.h>

#define BS 16
#define M  16
#define T  32
#define V  12000
#define P  64
#define PV 20

#define NCAP   (BS * M * T)     // 8192 caption-token rows
#define NPROGB 4                // 4 blocks x 256 threads = 1024 program rows

// ---------------------------------------------------------------------------
// Fused kernel:
//   blocks [0, NCAP)          : caption CE rows. Valid rows write partial NLL
//                               to ws[row]; masked rows exit WITHOUT writing
//                               (final kernel recomputes the mask and skips
//                               poisoned slots). No atomics, no zero-init.
//   blocks [NCAP, NCAP+NPROGB): program CE. Block-reduced partial NLL to
//                               ws[NCAP + pb].
// ---------------------------------------------------------------------------
__global__ __launch_bounds__(256) void fused_loss_kernel(
    const float* __restrict__ pred_cap,    // [BS,M,T,V]
    const int*   __restrict__ gt_cap,      // [BS,M,T]
    const int*   __restrict__ cap_lens,    // [BS,M]
    const int*   __restrict__ caps_count,  // [BS]
    const float* __restrict__ pred_prog,   // [BS,P,PV]
    const int*   __restrict__ gt_prog,     // [BS,P]
    const int*   __restrict__ prog_len,    // [BS]
    float*       __restrict__ ws)          // [NCAP + NPROGB] partials
{
    const int bid = blockIdx.x;
    __shared__ float sm[4], ss[4];

    if (bid < NCAP) {
        // ---- caption CE row ----
        const int t  = bid % T;
        const int bm = bid / T;
        const int m  = bm % M;
        const int b  = bm / M;
        if (t >= cap_lens[bm] || m >= caps_count[b]) return;  // no HBM row read

        const float4* p4 = (const float4*)(pred_cap + (size_t)bid * V);
        const int NV4 = V / 4;   // 3000

        float lmax = -INFINITY, lsum = 0.0f;
        for (int i = threadIdx.x; i < NV4; i += 256) {
            float4 x = p4[i];
            float m4 = fmaxf(fmaxf(x.x, x.y), fmaxf(x.z, x.w));
            float nm = fmaxf(lmax, m4);
            lsum = lsum * __expf(lmax - nm)
                 + __expf(x.x - nm) + __expf(x.y - nm)
                 + __expf(x.z - nm) + __expf(x.w - nm);
            lmax = nm;
        }
        // 64-lane online-softmax merge
        for (int off = 32; off > 0; off >>= 1) {
            float om = __shfl_down(lmax, off, 64);
            float os = __shfl_down(lsum, off, 64);
            float nm = fmaxf(lmax, om);
            lsum = lsum * __expf(lmax - nm) + os * __expf(om - nm);
            lmax = nm;
        }
        const int wave = threadIdx.x >> 6, lane = threadIdx.x & 63;
        if (lane == 0) { sm[wave] = lmax; ss[wave] = lsum; }
        __syncthreads();
        if (threadIdx.x == 0) {
            float gm = sm[0], gs = ss[0];
            #pragma unroll
            for (int w = 1; w < 4; w++) {
                float nm = fmaxf(gm, sm[w]);
                gs = gs * __expf(gm - nm) + ss[w] * __expf(sm[w] - nm);
                gm = nm;
            }
            const float xg = pred_cap[(size_t)bid * V + gt_cap[bid]];
            ws[bid] = logf(gs) + gm - xg;    // -(xg - gm - log(sum))
        }
    } else {
        // ---- program CE: 256 rows per block, one row per thread ----
        const int pb  = bid - NCAP;                // 0..3
        const int idx = pb * 256 + threadIdx.x;    // 0..1023 == b*P + p
        const int p   = idx % P;
        const int b   = idx / P;

        float nll = 0.0f;
        if (p < prog_len[b]) {
            const float* row = pred_prog + (size_t)idx * PV;
            float mx = row[0];
            #pragma unroll
            for (int i = 1; i < PV; i++) mx = fmaxf(mx, row[i]);
            float s = 0.0f;
            #pragma unroll
            for (int i = 0; i < PV; i++) s += __expf(row[i] - mx);
            nll = logf(s) + mx - row[gt_prog[idx]];
        }
        for (int off = 32; off > 0; off >>= 1) nll += __shfl_down(nll, off, 64);
        const int wave = threadIdx.x >> 6, lane = threadIdx.x & 63;
        if (lane == 0) ss[wave] = nll;
        __syncthreads();
        if (threadIdx.x == 0)
            ws[NCAP + pb] = ss[0] + ss[1] + ss[2] + ss[3];
    }
}

// ---------------------------------------------------------------------------
// Final kernel (1 block, 256 threads): masked sum of cap partials (mask
// recomputed -> poisoned slots skipped), prog partial sum, IoU, ragged
// counts, divisions, 4 outputs.
// ---------------------------------------------------------------------------
__global__ __launch_bounds__(256) void final_kernel(
    const int*   __restrict__ cap_lens,     // [BS,M]
    const int*   __restrict__ caps_count,   // [BS]
    const int*   __restrict__ prog_len,     // [BS]
    const float* __restrict__ gt_iv,        // [BS,M,2]
    const float* __restrict__ pred_iv,      // [BS,M,2]
    const float* __restrict__ ws,           // partials
    float*       __restrict__ out)          // [loss, cap, prog, iou]
{
    const int tid = threadIdx.x;            // also == b*M + m for per-caption work
    __shared__ int   s_len[BS * M];
    __shared__ int   s_cc[BS];
    __shared__ float red[6][256];

    s_len[tid] = cap_lens[tid];
    if (tid < BS) s_cc[tid] = caps_count[tid];
    __syncthreads();

    // masked sum of caption partials: 32 strided rows per thread
    float cap_sum = 0.0f;
    #pragma unroll
    for (int k = 0; k < NCAP / 256; k++) {
        const int r  = tid + k * 256;
        const int t  = r % T;
        const int bm = r / T;
        const int m  = bm % M;
        const int b  = bm / M;
        if (t < s_len[bm] && m < s_cc[b]) cap_sum += ws[r];
    }
    float prog_sum = (tid < NPROGB) ? ws[NCAP + tid] : 0.0f;

    // per-caption token count + IoU  (tid == b*M + m)
    const int m = tid % M, b = tid / M;
    const bool cvalid = (m < s_cc[b]);
    float ntok = cvalid ? (float)s_len[tid] : 0.0f;
    float iou = 0.0f;
    if (cvalid) {
        const float gs = gt_iv[tid * 2], ge = gt_iv[tid * 2 + 1];
        const float ps = pred_iv[tid * 2], pe = pred_iv[tid * 2 + 1];
        float inter = fmaxf(fminf(pe, ge) - fmaxf(ps, gs), 0.0f);
        const float uni = fmaxf(pe, ge) - fminf(ps, gs);
        iou = inter / fmaxf(uni, 1e-8f);
    }
    float nprog = (tid < BS) ? (float)prog_len[tid] : 0.0f;
    float ncaps = (tid < BS) ? (float)s_cc[tid]     : 0.0f;

    red[0][tid] = cap_sum; red[1][tid] = prog_sum; red[2][tid] = ntok;
    red[3][tid] = iou;     red[4][tid] = nprog;    red[5][tid] = ncaps;
    __syncthreads();
    for (int off = 128; off > 0; off >>= 1) {
        if (tid < off) {
            #pragma unroll
            for (int q = 0; q < 6; q++) red[q][tid] += red[q][tid + off];
        }
        __syncthreads();
    }
    if (tid == 0) {
        const float cap_loss  = red[0][0] / fmaxf(red[2][0], 1.0f);
        const float prog_loss = red[1][0] / fmaxf(red[4][0], 1.0f);
        const float iou_loss  = 1.0f - red[3][0] / fmaxf(red[5][0], 1.0f);
        out[0] = cap_loss + prog_loss;
        out[1] = cap_loss;
        out[2] = prog_loss;
        out[3] = iou_loss;
    }
}

extern "C" void kernel_launch(void* const* d_in, const int* in_sizes, int n_in,
                              void* d_out, int out_size, void* d_ws, size_t ws_size,
                              hipStream_t stream) {
    const int*   gt_captions    = (const int*)  d_in[0];
    const int*   gt_cap_lens    = (const int*)  d_in[1];
    const float* pred_captions  = (const float*)d_in[2];
    const int*   gt_program     = (const int*)  d_in[3];
    const int*   gt_prog_len    = (const int*)  d_in[4];
    const float* pred_program   = (const float*)d_in[5];
    const float* gt_intervals   = (const float*)d_in[6];
    const float* pred_intervals = (const float*)d_in[7];
    const int*   gt_caps_count  = (const int*)  d_in[8];
    // d_in[9] (pred_caps_count) unused by the reference math.

    float* ws  = (float*)d_ws;
    float* out = (float*)d_out;

    fused_loss_kernel<<<NCAP + NPROGB, 256, 0, stream>>>(
        pred_captions, gt_captions, gt_cap_lens, gt_caps_count,
        pred_program, gt_program, gt_prog_len, ws);

    final_kernel<<<1, 256, 0, stream>>>(
        gt_cap_lens, gt_caps_count, gt_prog_len,
        gt_intervals, pred_intervals, ws, out);
}